// Round 8
// baseline (204.709 us; speedup 1.0000x reference)
//
#include <hip/hip_runtime.h>

#define BSZ 8
#define SEQL 1024
#define CHN 1024
#define M1 (BSZ*SEQL)

typedef __attribute__((ext_vector_type(8))) short bf16x8;
typedef __attribute__((ext_vector_type(4))) float f32x4;
typedef __attribute__((ext_vector_type(4))) unsigned short us4;
typedef __attribute__((ext_vector_type(8))) unsigned short us8;

static __device__ __forceinline__ unsigned short f2bf(float f){
  unsigned int u = __float_as_uint(f);
  u += 0x7fffu + ((u >> 16) & 1u);
  return (unsigned short)(u >> 16);
}
static __device__ __forceinline__ float bf2f(unsigned short h){
  return __uint_as_float(((unsigned int)h) << 16);
}
static __device__ __forceinline__ void gload16(const void* g, void* l){
  __builtin_amdgcn_global_load_lds((const __attribute__((address_space(1))) void*)g,
                                   (__attribute__((address_space(3))) void*)l,
                                   16, 0, 0);
}
// swizzle for 32-short (64B, 4x16B-chunk) rows: phys chunk = c ^ s4(row)
static __device__ __forceinline__ int s4(int r){ return (r & 3) ^ ((r >> 2) & 3); }

#define SBAR() do { __builtin_amdgcn_sched_barrier(0); __builtin_amdgcn_s_barrier(); __builtin_amdgcn_sched_barrier(0); } while (0)
#define LGKM0() do { asm volatile("s_waitcnt lgkmcnt(0)" ::: "memory"); __builtin_amdgcn_sched_barrier(0); } while (0)
#define PRIO_HI() do { __builtin_amdgcn_s_setprio(1); __builtin_amdgcn_sched_barrier(0); } while (0)
#define PRIO_LO() do { __builtin_amdgcn_sched_barrier(0); __builtin_amdgcn_s_setprio(0); } while (0)

// ---------------- prep: fp32 -> bf16 conversions + exp(bias) ----------------
__global__ void prep_kernel(const float* __restrict__ x, const float* __restrict__ wq,
                            const float* __restrict__ wk, const float* __restrict__ wv,
                            const float* __restrict__ bias,
                            unsigned short* __restrict__ xb, unsigned short* __restrict__ wqb,
                            unsigned short* __restrict__ wkb, unsigned short* __restrict__ wvb,
                            unsigned short* __restrict__ ebb)
{
  const int NX = M1 * CHN;
  const int NW = CHN * CHN;
  const int total4 = (NX + 3 * NW + SEQL * SEQL) >> 2;
  for (int i = blockIdx.x * blockDim.x + threadIdx.x; i < total4;
       i += gridDim.x * blockDim.x) {
    int e = i << 2;
    const float* src; unsigned short* dst; int off; bool ex = false;
    if (e < NX)               { src = x;    dst = xb;  off = e; }
    else if (e < NX + NW)     { src = wq;   dst = wqb; off = e - NX; }
    else if (e < NX + 2 * NW) { src = wk;   dst = wkb; off = e - (NX + NW); }
    else if (e < NX + 3 * NW) { src = wv;   dst = wvb; off = e - (NX + 2 * NW); }
    else                      { src = bias; dst = ebb; off = e - (NX + 3 * NW); ex = true; }
    float4 v = *reinterpret_cast<const float4*>(src + off);
    if (ex) { v.x = expf(v.x); v.y = expf(v.y); v.z = expf(v.z); v.w = expf(v.w); }
    us4 o; o.x = f2bf(v.x); o.y = f2bf(v.y); o.z = f2bf(v.z); o.w = f2bf(v.w);
    *reinterpret_cast<us4*>(dst + off) = o;
  }
}

// ---------------- gemm_qkv: BM=128, BN=128x3, 32 K-phases, dbuf 64K, 2 blk/CU ----
// 8 waves 2Mx4N -> wave tile 64 rows x 32 cols x 3 mats (acc 96 VGPR).
__global__ __launch_bounds__(512, 2) void gemm_qkv(
    const unsigned short* __restrict__ Xb,
    const unsigned short* __restrict__ Wq, const unsigned short* __restrict__ Wk,
    const unsigned short* __restrict__ Wv,
    const float* __restrict__ bq, const float* __restrict__ bk,
    const float* __restrict__ bv,
    unsigned short* __restrict__ Qb,
    unsigned short* __restrict__ EKT, unsigned short* __restrict__ EKVT)
{
  __shared__ unsigned short lds[2 * 16384];  // per buf: A 128x32 (4096) | 3x W 128x32 (4096 each)
  const int tid = threadIdx.x;
  const int lane = tid & 63;
  const int wid = tid >> 6;
  const int wm = wid >> 2;               // 0..1 -> 64-row strip
  const int wn = wid & 3;                // 0..3 -> 32-col strip per mat
  const int lid = blockIdx.x;            // grid 512
  const int sid = (lid & 7) * 64 + (lid >> 3);
  const int m0 = (sid & 63) * 128;       // m fastest: W panel (0.75MB) L2-resident per XCD
  const int n0 = (sid >> 6) * 128;       // 8 n-panels, one per XCD

  // staging addresses (1 A-chunk + 3 B-chunks per thread per phase)
  const int srow = tid >> 2, sc = tid & 3;
  const int scol = ((sc ^ s4(srow)) * 8);
  const unsigned short* gA = Xb + (m0 + srow) * CHN + scol;
  const unsigned short* gB0 = Wq + (n0 + srow) * CHN + scol;
  const unsigned short* gB1 = Wk + (n0 + srow) * CHN + scol;
  const unsigned short* gB2 = Wv + (n0 + srow) * CHN + scol;
  const int dA = tid * 8;
  const int dB = 4096 + tid * 8;         // +w*4096

  int aOff[4], bOff[2];
  const int c0 = lane >> 4;
#pragma unroll
  for (int mi = 0; mi < 4; mi++) {
    int r = wm * 64 + mi * 16 + (lane & 15);
    aOff[mi] = r * 32 + (c0 ^ s4(r)) * 8;
  }
#pragma unroll
  for (int ni = 0; ni < 2; ni++) {
    int r = wn * 32 + ni * 16 + (lane & 15);
    bOff[ni] = r * 32 + (c0 ^ s4(r)) * 8;
  }

  f32x4 accq[4][2] = {}, acck[4][2] = {}, accv[4][2] = {};

  // prologue: stage phase 0 into buf0
  gload16(gA, lds + dA);
  gload16(gB0, lds + dB);
  gload16(gB1, lds + dB + 4096);
  gload16(gB2, lds + dB + 8192);

  for (int j = 0; j < 32; ++j) {
    const int cur = (j & 1) * 16384;
    const int nxt = 16384 - cur;
    const int kn = (j + 1) << 5;
    if (j < 31) {
      gload16(gA + kn, lds + nxt + dA);
      gload16(gB0 + kn, lds + nxt + dB);
      gload16(gB1 + kn, lds + nxt + dB + 4096);
      gload16(gB2 + kn, lds + nxt + dB + 8192);
      asm volatile("s_waitcnt vmcnt(4)" ::: "memory");
    } else {
      asm volatile("s_waitcnt vmcnt(0)" ::: "memory");
    }
    SBAR();   // all waves' phase-j staging resident
    bf16x8 af[4], bqf[2], bkf[2], bvf[2];
#pragma unroll
    for (int mi = 0; mi < 4; mi++)
      af[mi] = *reinterpret_cast<const bf16x8*>(lds + cur + aOff[mi]);
#pragma unroll
    for (int ni = 0; ni < 2; ni++) {
      bqf[ni] = *reinterpret_cast<const bf16x8*>(lds + cur + 4096  + bOff[ni]);
      bkf[ni] = *reinterpret_cast<const bf16x8*>(lds + cur + 8192  + bOff[ni]);
      bvf[ni] = *reinterpret_cast<const bf16x8*>(lds + cur + 12288 + bOff[ni]);
    }
    LGKM0();
    PRIO_HI();
#pragma unroll
    for (int mi = 0; mi < 4; mi++)
#pragma unroll
      for (int ni = 0; ni < 2; ni++) {
        accq[mi][ni] = __builtin_amdgcn_mfma_f32_16x16x32_bf16(af[mi], bqf[ni], accq[mi][ni], 0, 0, 0);
        acck[mi][ni] = __builtin_amdgcn_mfma_f32_16x16x32_bf16(af[mi], bkf[ni], acck[mi][ni], 0, 0, 0);
        accv[mi][ni] = __builtin_amdgcn_mfma_f32_16x16x32_bf16(af[mi], bvf[ni], accv[mi][ni], 0, 0, 0);
      }
    PRIO_LO();
    SBAR();   // retire reads of cur before next phase overwrites it
  }

  // ---- epilogue ----
  const int bIdx = m0 >> 10;
  const int s0 = m0 & 1023;
  const int rbq = (lane >> 4) * 4;
  float bqv[2], bkv[2], bvv[2];
#pragma unroll
  for (int ni = 0; ni < 2; ni++) {
    int c = n0 + wn * 32 + ni * 16 + (lane & 15);
    bqv[ni] = bq[c]; bkv[ni] = bk[c]; bvv[ni] = bv[c];
  }
#pragma unroll
  for (int mi = 0; mi < 4; mi++)
#pragma unroll
    for (int ni = 0; ni < 2; ni++) {
      int col = n0 + wn * 32 + ni * 16 + (lane & 15);
#pragma unroll
      for (int r = 0; r < 4; r++) {
        int mrow = m0 + wm * 64 + mi * 16 + rbq + r;
        Qb[mrow * CHN + col] = f2bf(accq[mi][ni][r] + bqv[ni]);
        float ekf = expf(acck[mi][ni][r] + bkv[ni]);
        acck[mi][ni][r] = ekf;
        accv[mi][ni][r] = ekf * (accv[mi][ni][r] + bvv[ni]);
      }
    }
  // pass 1: ek -> LDS transpose ([128 c][128+8 s]) -> EKT
#pragma unroll
  for (int mi = 0; mi < 4; mi++)
#pragma unroll
    for (int ni = 0; ni < 2; ni++) {
      int nloc = wn * 32 + ni * 16 + (lane & 15);
#pragma unroll
      for (int r = 0; r < 4; r++)
        lds[nloc * 136 + wm * 64 + mi * 16 + rbq + r] = f2bf(acck[mi][ni][r]);
    }
  __syncthreads();
#pragma unroll
  for (int it = 0; it < 4; it++) {
    int ch = it * 512 + tid;
    int nloc = ch >> 4, c8 = ch & 15;
    us8 v = *reinterpret_cast<const us8*>(lds + nloc * 136 + c8 * 8);
    *reinterpret_cast<us8*>(EKT + (bIdx * CHN + n0 + nloc) * SEQL + s0 + c8 * 8) = v;
  }
  __syncthreads();
  // pass 2: ekv -> LDS transpose -> EKVT
#pragma unroll
  for (int mi = 0; mi < 4; mi++)
#pragma unroll
    for (int ni = 0; ni < 2; ni++) {
      int nloc = wn * 32 + ni * 16 + (lane & 15);
#pragma unroll
      for (int r = 0; r < 4; r++)
        lds[nloc * 136 + wm * 64 + mi * 16 + rbq + r] = f2bf(accv[mi][ni][r]);
    }
  __syncthreads();
#pragma unroll
  for (int it = 0; it < 4; it++) {
    int ch = it * 512 + tid;
    int nloc = ch >> 4, c8 = ch & 15;
    us8 v = *reinterpret_cast<const us8*>(lds + nloc * 136 + c8 * 8);
    *reinterpret_cast<us8*>(EKVT + (bIdx * CHN + n0 + nloc) * SEQL + s0 + c8 * 8) = v;
  }
}

// ---------------- gemm_aft: BM=256(t), BN=64x{EKT,EKVT}, 32 K-phases, dbuf 48K, 2 blk/CU ----
// 8 waves 4Mx2N -> wave tile 64 t-rows x 32 cols x 2 mats (acc 64 VGPR).
__global__ __launch_bounds__(512, 2) void gemm_aft(
    const unsigned short* __restrict__ EB,
    const unsigned short* __restrict__ EKT, const unsigned short* __restrict__ EKVT,
    const unsigned short* __restrict__ Qb, float* __restrict__ out)
{
  __shared__ unsigned short lds[2 * 12288];  // per buf: A 256x32 (8192) | 2x B 64x32 (2048 each)
  const int tid = threadIdx.x;
  const int lane = tid & 63;
  const int wid = tid >> 6;
  const int wm = wid >> 1;               // 0..3 -> 64-row t-strip
  const int wn = wid & 1;                // 0..1 -> 32-col strip per mat
  const int lid = blockIdx.x;            // grid 512
  const int sid = (lid & 7) * 64 + (lid >> 3);
  const int t0 = (sid & 3) * 256;        // t fastest: B panel (256K) + EB (2M) L2-resident
  const int n0 = (sid >> 2) * 64;

  // staging: A 2 chunks/thread, B 1 chunk/thread
  const int ar0 = tid >> 2, ac0 = tid & 3;
  const int ar1 = (tid + 512) >> 2, ac1 = tid & 3;
  const unsigned short* gA0 = EB + (t0 + ar0) * SEQL + (ac0 ^ s4(ar0)) * 8;
  const unsigned short* gA1 = EB + (t0 + ar1) * SEQL + (ac1 ^ s4(ar1)) * 8;
  const int dA0 = tid * 8, dA1 = (tid + 512) * 8;
  const int bw = tid >> 8;               // 0: EKT, 1: EKVT
  const int bch = tid & 255;
  const int brow = bch >> 2, bc = bch & 3;
  const unsigned short* gB = (bw ? EKVT : EKT) + (n0 + brow) * SEQL + (bc ^ s4(brow)) * 8;
  const int dB = 8192 + bw * 2048 + bch * 8;

  int aOff[4], bOff[2];
  const int c0 = lane >> 4;
#pragma unroll
  for (int mi = 0; mi < 4; mi++) {
    int r = wm * 64 + mi * 16 + (lane & 15);
    aOff[mi] = r * 32 + (c0 ^ s4(r)) * 8;
  }
#pragma unroll
  for (int ni = 0; ni < 2; ni++) {
    int r = wn * 32 + ni * 16 + (lane & 15);
    bOff[ni] = r * 32 + (c0 ^ s4(r)) * 8;
  }

  f32x4 accd[4][2] = {}, accn[4][2] = {};

  gload16(gA0, lds + dA0);
  gload16(gA1, lds + dA1);
  gload16(gB, lds + dB);

  for (int j = 0; j < 32; ++j) {
    const int cur = (j & 1) * 12288;
    const int nxt = 12288 - cur;
    const int kn = (j + 1) << 5;
    if (j < 31) {
      gload16(gA0 + kn, lds + nxt + dA0);
      gload16(gA1 + kn, lds + nxt + dA1);
      gload16(gB + kn, lds + nxt + dB);
      asm volatile("s_waitcnt vmcnt(3)" ::: "memory");
    } else {
      asm volatile("s_waitcnt vmcnt(0)" ::: "memory");
    }
    SBAR();
    bf16x8 af[4], bdf[2], bnf[2];
#pragma unroll
    for (int mi = 0; mi < 4; mi++)
      af[mi] = *reinterpret_cast<const bf16x8*>(lds + cur + aOff[mi]);
#pragma unroll
    for (int ni = 0; ni < 2; ni++) {
      bdf[ni] = *reinterpret_cast<const bf16x8*>(lds + cur + 8192  + bOff[ni]);
      bnf[ni] = *reinterpret_cast<const bf16x8*>(lds + cur + 10240 + bOff[ni]);
    }
    LGKM0();
    PRIO_HI();
#pragma unroll
    for (int mi = 0; mi < 4; mi++)
#pragma unroll
      for (int ni = 0; ni < 2; ni++) {
        accd[mi][ni] = __builtin_amdgcn_mfma_f32_16x16x32_bf16(af[mi], bdf[ni], accd[mi][ni], 0, 0, 0);
        accn[mi][ni] = __builtin_amdgcn_mfma_f32_16x16x32_bf16(af[mi], bnf[ni], accn[mi][ni], 0, 0, 0);
      }
    PRIO_LO();
    SBAR();
  }

  const int rbq = (lane >> 4) * 4;
#pragma unroll
  for (int mi = 0; mi < 4; mi++)
#pragma unroll
    for (int ni = 0; ni < 2; ni++) {
      int nloc = wn * 32 + ni * 16 + (lane & 15);
      int n = n0 + nloc;
      int b = n >> 10, c = n & 1023;
#pragma unroll
      for (int r = 0; r < 4; r++) {
        int tt = t0 + wm * 64 + mi * 16 + rbq + r;
        float qv = bf2f(Qb[(b * SEQL + tt) * CHN + c]);
        float sig = 1.0f / (1.0f + expf(-qv));
        out[(b * SEQL + tt) * CHN + c] = sig * accn[mi][ni][r] / accd[mi][ni][r];
      }
    }
}

extern "C" void kernel_launch(void* const* d_in, const int* in_sizes, int n_in,
                              void* d_out, int out_size, void* d_ws, size_t ws_size,
                              hipStream_t stream) {
  (void)in_sizes; (void)n_in; (void)out_size; (void)ws_size;
  const float* x    = (const float*)d_in[0];
  const float* wq   = (const float*)d_in[1];
  const float* wk   = (const float*)d_in[2];
  const float* wv   = (const float*)d_in[3];
  const float* bq   = (const float*)d_in[4];
  const float* bk   = (const float*)d_in[5];
  const float* bv   = (const float*)d_in[6];
  const float* bias = (const float*)d_in[7];
  float* out = (float*)d_out;

  char* ws = (char*)d_ws;
  const size_t MB = 1024 * 1024;
  unsigned short* Xb   = (unsigned short*)(ws);
  unsigned short* Wqb  = (unsigned short*)(ws + 16 * MB);
  unsigned short* Wkb  = (unsigned short*)(ws + 18 * MB);
  unsigned short* Wvb  = (unsigned short*)(ws + 20 * MB);
  unsigned short* EBb  = (unsigned short*)(ws + 22 * MB);
  unsigned short* Qb   = (unsigned short*)(ws + 24 * MB);
  unsigned short* EKT  = (unsigned short*)(ws + 40 * MB);
  unsigned short* EKVT = (unsigned short*)(ws + 56 * MB);

  prep_kernel<<<2048, 256, 0, stream>>>(x, wq, wk, wv, bias, Xb, Wqb, Wkb, Wvb, EBb);
  gemm_qkv<<<512, 512, 0, stream>>>(Xb, Wqb, Wkb, Wvb, bq, bk, bv, Qb, EKT, EKVT);
  gemm_aft<<<512, 512, 0, stream>>>(EBb, EKT, EKVT, Qb, out);
}

// Round 9
// 199.248 us; speedup vs baseline: 1.0274x; 1.0274x over previous
//
#include <hip/hip_runtime.h>

#define BSZ 8
#define SEQL 1024
#define CHN 1024
#define M1 (BSZ*SEQL)

typedef __attribute__((ext_vector_type(8))) short bf16x8;
typedef __attribute__((ext_vector_type(4))) float f32x4;
typedef __attribute__((ext_vector_type(4))) unsigned short us4;
typedef __attribute__((ext_vector_type(8))) unsigned short us8;

static __device__ __forceinline__ unsigned short f2bf(float f){
  unsigned int u = __float_as_uint(f);
  u += 0x7fffu + ((u >> 16) & 1u);
  return (unsigned short)(u >> 16);
}
static __device__ __forceinline__ float bf2f(unsigned short h){
  return __uint_as_float(((unsigned int)h) << 16);
}
static __device__ __forceinline__ void gload16(const void* g, void* l){
  __builtin_amdgcn_global_load_lds((const __attribute__((address_space(1))) void*)g,
                                   (__attribute__((address_space(3))) void*)l,
                                   16, 0, 0);
}

#define SBAR() do { __builtin_amdgcn_sched_barrier(0); __builtin_amdgcn_s_barrier(); __builtin_amdgcn_sched_barrier(0); } while (0)
#define LGKM0() do { asm volatile("s_waitcnt lgkmcnt(0)" ::: "memory"); __builtin_amdgcn_sched_barrier(0); } while (0)
#define PRIO_HI() do { __builtin_amdgcn_s_setprio(1); __builtin_amdgcn_sched_barrier(0); } while (0)
#define PRIO_LO() do { __builtin_amdgcn_sched_barrier(0); __builtin_amdgcn_s_setprio(0); } while (0)

// ---------------- prep: fp32 -> bf16 conversions + exp(bias) (R6 verbatim) ----
__global__ void prep_kernel(const float* __restrict__ x, const float* __restrict__ wq,
                            const float* __restrict__ wk, const float* __restrict__ wv,
                            const float* __restrict__ bias,
                            unsigned short* __restrict__ xb, unsigned short* __restrict__ wqb,
                            unsigned short* __restrict__ wkb, unsigned short* __restrict__ wvb,
                            unsigned short* __restrict__ ebb)
{
  const int NX = M1 * CHN;
  const int NW = CHN * CHN;
  const int total4 = (NX + 3 * NW + SEQL * SEQL) >> 2;
  for (int i = blockIdx.x * blockDim.x + threadIdx.x; i < total4;
       i += gridDim.x * blockDim.x) {
    int e = i << 2;
    const float* src; unsigned short* dst; int off; bool ex = false;
    if (e < NX)               { src = x;    dst = xb;  off = e; }
    else if (e < NX + NW)     { src = wq;   dst = wqb; off = e - NX; }
    else if (e < NX + 2 * NW) { src = wk;   dst = wkb; off = e - (NX + NW); }
    else if (e < NX + 3 * NW) { src = wv;   dst = wvb; off = e - (NX + 2 * NW); }
    else                      { src = bias; dst = ebb; off = e - (NX + 3 * NW); ex = true; }
    float4 v = *reinterpret_cast<const float4*>(src + off);
    if (ex) { v.x = expf(v.x); v.y = expf(v.y); v.z = expf(v.z); v.w = expf(v.w); }
    us4 o; o.x = f2bf(v.x); o.y = f2bf(v.y); o.z = f2bf(v.z); o.w = f2bf(v.w);
    *reinterpret_cast<us4*>(dst + off) = o;
  }
}

// ---------------- gemm_qkv: BM=256, BN=64x3, BK=64, 6 fine phases/K-tile ------
// 8 waves 2Mx4N -> wave tile 128 rows x 16 cols per mat. acc[3][8] = 96 VGPR.
// LDS per buf: A[256][64] (32K) | B[192][64] (24K); dbuf 112K -> 1 block/CU.
__global__ __launch_bounds__(512, 2) void gemm_qkv(
    const unsigned short* __restrict__ Xb,
    const unsigned short* __restrict__ Wq, const unsigned short* __restrict__ Wk,
    const unsigned short* __restrict__ Wv,
    const float* __restrict__ bq, const float* __restrict__ bk,
    const float* __restrict__ bv,
    unsigned short* __restrict__ Qb,
    unsigned short* __restrict__ EKT, unsigned short* __restrict__ EKVT)
{
  __shared__ unsigned short lds[2 * 28672];
  const int tid = threadIdx.x;
  const int lane = tid & 63;
  const int wid = tid >> 6;
  const int wm = wid >> 2;               // 0..1 -> 128-row strip
  const int wn = wid & 3;                // 0..3 -> 16-col strip per mat
  const int lid = blockIdx.x;            // grid 512
  const int sid = (lid & 7) * 64 + (lid >> 3);
  const int m0 = (sid >> 4) * 256;       // n fastest in XCD chunk (R6-proven)
  const int n0 = (sid & 15) * 64;

  // A staging: 4 batches of 8KB over [256 rows][64 shorts]; pre-swizzled src
  const unsigned short* srcA[4]; int dA[4];
#pragma unroll
  for (int p = 0; p < 4; p++) {
    int l = p * 8192 + tid * 16;         // byte offset in 32KB A tile
    int row = l >> 7;
    int ch = (l >> 4) & 7;
    srcA[p] = Xb + (m0 + row) * CHN + (ch ^ (row & 7)) * 8;
    dA[p] = l >> 1;
  }
  // B staging: 3 batches of 8KB; batch w = rows [w*64, w*64+64) = mat w
  const unsigned short* srcB[3]; int dB[3];
#pragma unroll
  for (int w = 0; w < 3; w++) {
    int l = w * 8192 + tid * 16;
    int brow = l >> 7;                   // 0..191
    int ch = (l >> 4) & 7;
    const unsigned short* W = (w == 0) ? Wq : (w == 1) ? Wk : Wv;
    srcB[w] = W + (n0 + (brow & 63)) * CHN + (ch ^ (brow & 7)) * 8;
    dB[w] = 16384 + (l >> 1);
  }

  int aOff[8][2], bOff[3][2];
#pragma unroll
  for (int mi = 0; mi < 8; mi++) {
    int r = wm * 128 + mi * 16 + (lane & 15);
#pragma unroll
    for (int ks = 0; ks < 2; ks++)
      aOff[mi][ks] = r * 64 + ((((ks << 2) + (lane >> 4)) ^ (r & 7)) << 3);
  }
#pragma unroll
  for (int mat = 0; mat < 3; mat++) {
    int r = mat * 64 + wn * 16 + (lane & 15);
#pragma unroll
    for (int ks = 0; ks < 2; ks++)
      bOff[mat][ks] = 16384 + r * 64 + ((((ks << 2) + (lane >> 4)) ^ (r & 7)) << 3);
  }

  f32x4 acc[3][8] = {};                  // [mat][mi]

  // prologue: tile 0 -> buf0
#pragma unroll
  for (int p = 0; p < 4; p++) gload16(srcA[p], lds + dA[p]);
#pragma unroll
  for (int w = 0; w < 3; w++) gload16(srcB[w], lds + dB[w]);

  for (int t = 0; t < 16; ++t) {
    const int cur = (t & 1) * 28672;
    const int nxt = 28672 - cur;
    const int kn = (t + 1) << 6;
    if (t < 15) {
#pragma unroll
      for (int p = 0; p < 4; p++) gload16(srcA[p] + kn, lds + nxt + dA[p]);
#pragma unroll
      for (int w = 0; w < 3; w++) gload16(srcB[w] + kn, lds + nxt + dB[w]);
      // FIFO: [tile t x7, tile t+1 x7] -> keep 7 newest: tile t landed
      asm volatile("s_waitcnt vmcnt(7)" ::: "memory");
    } else {
      asm volatile("s_waitcnt vmcnt(0)" ::: "memory");
    }
    SBAR();   // all waves' tile-t staging resident
#pragma unroll
    for (int ks = 0; ks < 2; ks++) {
      bf16x8 af[8];
#pragma unroll
      for (int mi = 0; mi < 8; mi++)
        af[mi] = *reinterpret_cast<const bf16x8*>(lds + cur + aOff[mi][ks]);
#pragma unroll
      for (int mat = 0; mat < 3; mat++) {
        bf16x8 bf = *reinterpret_cast<const bf16x8*>(lds + cur + bOff[mat][ks]);
        LGKM0();
        PRIO_HI();
#pragma unroll
        for (int mi = 0; mi < 8; mi++)
          acc[mat][mi] = __builtin_amdgcn_mfma_f32_16x16x32_bf16(af[mi], bf, acc[mat][mi], 0, 0, 0);
        PRIO_LO();
        SBAR();   // phase boundary; final one doubles as end-of-tile barrier
      }
    }
  }

  // ---- epilogue ----
  const int bIdx = m0 >> 10;
  const int s0 = m0 & 1023;
  const int rbq = (lane >> 4) * 4;
  const int colLoc = wn * 16 + (lane & 15);   // 0..63 (one col per lane per mat)
  const float bqv = bq[n0 + colLoc];
  const float bkv = bk[n0 + colLoc];
  const float bvv = bv[n0 + colLoc];
#pragma unroll
  for (int mi = 0; mi < 8; mi++)
#pragma unroll
    for (int r = 0; r < 4; r++) {
      int mrow = m0 + wm * 128 + mi * 16 + rbq + r;
      Qb[mrow * CHN + n0 + colLoc] = f2bf(acc[0][mi][r] + bqv);
      float ekf = expf(acc[1][mi][r] + bkv);
      acc[1][mi][r] = ekf;
      acc[2][mi][r] = ekf * (acc[2][mi][r] + bvv);
    }
  // pass 1: ek -> LDS transpose ([64 n][256+8 s]) -> EKT
#pragma unroll
  for (int mi = 0; mi < 8; mi++)
#pragma unroll
    for (int r = 0; r < 4; r++)
      lds[colLoc * 264 + wm * 128 + mi * 16 + rbq + r] = f2bf(acc[1][mi][r]);
  __syncthreads();
#pragma unroll
  for (int it = 0; it < 4; it++) {
    int ch = it * 512 + tid;
    int nloc = ch >> 5, c8 = ch & 31;
    us8 v = *reinterpret_cast<const us8*>(lds + nloc * 264 + c8 * 8);
    *reinterpret_cast<us8*>(EKT + (bIdx * CHN + n0 + nloc) * SEQL + s0 + c8 * 8) = v;
  }
  __syncthreads();
  // pass 2: ekv -> LDS transpose -> EKVT
#pragma unroll
  for (int mi = 0; mi < 8; mi++)
#pragma unroll
    for (int r = 0; r < 4; r++)
      lds[colLoc * 264 + wm * 128 + mi * 16 + rbq + r] = f2bf(acc[2][mi][r]);
  __syncthreads();
#pragma unroll
  for (int it = 0; it < 4; it++) {
    int ch = it * 512 + tid;
    int nloc = ch >> 5, c8 = ch & 31;
    us8 v = *reinterpret_cast<const us8*>(lds + nloc * 264 + c8 * 8);
    *reinterpret_cast<us8*>(EKVT + (bIdx * CHN + n0 + nloc) * SEQL + s0 + c8 * 8) = v;
  }
}

// ---------------- gemm_aft: R6 verbatim (BM=128, BN=64x2, BK=64, dbuf) -------
__global__ __launch_bounds__(512, 4) void gemm_aft(
    const unsigned short* __restrict__ EB,
    const unsigned short* __restrict__ EKT, const unsigned short* __restrict__ EKVT,
    const unsigned short* __restrict__ Qb, float* __restrict__ out)
{
  __shared__ unsigned short lds[2 * 16384];  // per buf: A 8192 | Bd 4096 | Bn 4096
  const int tid = threadIdx.x;
  const int lane = tid & 63;
  const int wid = tid >> 6;
  const int wm = wid >> 1;
  const int wn = wid & 1;
  const int nwg = gridDim.x;             // 1024
  const int lid = blockIdx.x;
  const int sid = (lid & 7) * (nwg >> 3) + (lid >> 3);
  const int t0 = (sid & 7) * 128;        // t fastest: B panels L2-resident
  const int n0 = (sid >> 3) * 64;

  const unsigned short* srcA[2]; int dA[2];
#pragma unroll
  for (int p = 0; p < 2; p++) {
    int l = p * 8192 + tid * 16;
    int row = l >> 7;
    int lc = ((l >> 4) & 7) ^ (row & 7);
    srcA[p] = EB + (t0 + row) * SEQL + lc * 8;
    dA[p] = l >> 1;
  }
  const unsigned short* srcB[2]; int dB[2];
  {
    int l = tid * 16;
    int row = l >> 7;
    int lc = ((l >> 4) & 7) ^ (row & 7);
#pragma unroll
    for (int w = 0; w < 2; w++) {
      const unsigned short* B = (w == 0) ? EKT : EKVT;
      srcB[w] = B + (n0 + row) * SEQL + lc * 8;
      dB[w] = 8192 + w * 4096 + (l >> 1);
    }
  }

  int aOff[2][2], bOff[2][2];
#pragma unroll
  for (int mi = 0; mi < 2; mi++) {
    int r = wm * 32 + mi * 16 + (lane & 15);
#pragma unroll
    for (int ks = 0; ks < 2; ks++)
      aOff[mi][ks] = r * 64 + ((((ks << 2) + (lane >> 4)) ^ (r & 7)) << 3);
  }
#pragma unroll
  for (int ni = 0; ni < 2; ni++) {
    int r = wn * 32 + ni * 16 + (lane & 15);
#pragma unroll
    for (int ks = 0; ks < 2; ks++)
      bOff[ni][ks] = r * 64 + ((((ks << 2) + (lane >> 4)) ^ (r & 7)) << 3);
  }

  f32x4 accd[2][2] = {}, accn[2][2] = {};

#pragma unroll
  for (int p = 0; p < 2; p++) gload16(srcA[p], lds + dA[p]);
#pragma unroll
  for (int w = 0; w < 2; w++) gload16(srcB[w], lds + dB[w]);

  for (int t = 0; t < 16; ++t) {
    const int cur = (t & 1) * 16384;
    const int nxt = 16384 - cur;
    const int kn = (t + 1) << 6;
    if (t < 15) {
#pragma unroll
      for (int p = 0; p < 2; p++) gload16(srcA[p] + kn, lds + nxt + dA[p]);
      asm volatile("s_waitcnt vmcnt(2)" ::: "memory");
    } else {
      asm volatile("s_waitcnt vmcnt(0)" ::: "memory");
    }
    SBAR();   // readiness: ALL waves' tile-t staging resident
#pragma unroll
    for (int ks = 0; ks < 2; ks++) {
      bf16x8 af[2], bdf[2], bnf[2];
#pragma unroll
      for (int mi = 0; mi < 2; mi++)
        af[mi] = *reinterpret_cast<const bf16x8*>(lds + cur + aOff[mi][ks]);
#pragma unroll
      for (int ni = 0; ni < 2; ni++) {
        bdf[ni] = *reinterpret_cast<const bf16x8*>(lds + cur + 8192  + bOff[ni][ks]);
        bnf[ni] = *reinterpret_cast<const bf16x8*>(lds + cur + 12288 + bOff[ni][ks]);
      }
      PRIO_HI();
#pragma unroll
      for (int ni = 0; ni < 2; ni++)
#pragma unroll
        for (int mi = 0; mi < 2; mi++) {
          accd[mi][ni] = __builtin_amdgcn_mfma_f32_16x16x32_bf16(af[mi], bdf[ni], accd[mi][ni], 0, 0, 0);
          accn[mi][ni] = __builtin_amdgcn_mfma_f32_16x16x32_bf16(af[mi], bnf[ni], accn[mi][ni], 0, 0, 0);
        }
      PRIO_LO();
      if (ks == 0 && t < 15) {
#pragma unroll
        for (int w = 0; w < 2; w++) gload16(srcB[w] + kn, lds + nxt + dB[w]);
      }
    }
    LGKM0();
    SBAR();   // end-of-iter
  }

  const int rbq = (lane >> 4) * 4;
#pragma unroll
  for (int mi = 0; mi < 2; mi++)
#pragma unroll
    for (int ni = 0; ni < 2; ni++) {
      int nloc = wn * 32 + ni * 16 + (lane & 15);
      int n = n0 + nloc;
      int b = n >> 10, c = n & 1023;
#pragma unroll
      for (int r = 0; r < 4; r++) {
        int t = t0 + wm * 32 + mi * 16 + rbq + r;
        float qv = bf2f(Qb[(b * SEQL + t) * CHN + c]);
        float sig = 1.0f / (1.0f + expf(-qv));
        out[(b * SEQL + t) * CHN + c] = sig * accn[mi][ni][r] / accd[mi][ni][r];
      }
    }
}

extern "C" void kernel_launch(void* const* d_in, const int* in_sizes, int n_in,
                              void* d_out, int out_size, void* d_ws, size_t ws_size,
                              hipStream_t stream) {
  (void)in_sizes; (void)n_in; (void)out_size; (void)ws_size;
  const float* x    = (const float*)d_in[0];
  const float* wq   = (const float*)d_in[1];
  const float* wk   = (const float*)d_in[2];
  const float* wv   = (const float*)d_in[3];
  const float* bq   = (const float*)d_in[4];
  const float* bk   = (const float*)d_in[5];
  const float* bv   = (const float*)d_in[6];
  const float* bias = (const float*)d_in[7];
  float* out = (float*)d_out;

  char* ws = (char*)d_ws;
  const size_t MB = 1024 * 1024;
  unsigned short* Xb   = (unsigned short*)(ws);
  unsigned short* Wqb  = (unsigned short*)(ws + 16 * MB);
  unsigned short* Wkb  = (unsigned short*)(ws + 18 * MB);
  unsigned short* Wvb  = (unsigned short*)(ws + 20 * MB);
  unsigned short* EBb  = (unsigned short*)(ws + 22 * MB);
  unsigned short* Qb   = (unsigned short*)(ws + 24 * MB);
  unsigned short* EKT  = (unsigned short*)(ws + 40 * MB);
  unsigned short* EKVT = (unsigned short*)(ws + 56 * MB);

  prep_kernel<<<2048, 256, 0, stream>>>(x, wq, wk, wv, bias, Xb, Wqb, Wkb, Wvb, EBb);
  gemm_qkv<<<512, 512, 0, stream>>>(Xb, Wqb, Wkb, Wvb, bq, bk, bv, Qb, EKT, EKVT);
  gemm_aft<<<1024, 512, 0, stream>>>(EBb, EKT, EKVT, Qb, out);
}